// Round 2
// baseline (153.362 us; speedup 1.0000x reference)
//
#include <hip/hip_runtime.h>

// DGraFormer graph-propagation block, algebraically collapsed to 6 matvecs
// of A=adj[b,s,:,:] (64x64) per (b,s). See round-0 derivation:
//   out[n] = sum_k P'_k y_k[n] + sum_k Q_k u_k[n] + (Q_0 + b_mlp)
// with y_k = (0.95 A^T)^k x[b,:,s], u_k = (0.95 A^T)^k 1.
// Memory-bound: one pass over adj (176 MB). This revision:
//  - dwordx4 adj loads (16 instr/wave instead of 64)
//  - lane-parallel MLP fold + shfl butterfly (was 384 redundant FMAs/thread)
//  - matvec split: lane holds rows == h (mod 4) x 4 cols; xor16/32 reduce.

#define BB 32
#define NN 64
#define SS 336
#define DD 32
#define BETA 0.05f
#define OMB 0.95f

#define WAITLDS() __asm__ volatile("s_waitcnt lgkmcnt(0)" ::: "memory")

__global__ __launch_bounds__(256, 4) void dgra_collapsed_kernel(
    const float* __restrict__ x, const float* __restrict__ adj,
    const float* __restrict__ w_start, const float* __restrict__ b_start,
    const float* __restrict__ w_mlp, const float* __restrict__ b_mlp,
    float* __restrict__ out)
{
    const int tid  = threadIdx.x;
    const int lane = tid & 63;
    const int w    = tid >> 6;           // wave id = s within the s4 tile
    const int blk  = blockIdx.x;
    const int b    = blk / (SS / 4);
    const int s4   = blk % (SS / 4);
    const int s    = s4 * 4 + w;

    const int h = lane >> 4;             // row residue class (mod 4)
    const int q = lane & 15;             // column group: cols 4q..4q+3

    // ---- stage A: 16 x dwordx4, lane l gets av[i].j = A[4i+h][4q+j] ----
    const float* Ab = adj + (size_t)(b * SS + s) * (NN * NN);
    float4 av[16];
#pragma unroll
    for (int i = 0; i < 16; ++i)
        av[i] = *reinterpret_cast<const float4*>(Ab + i * 256 + lane * 4);

    // ---- lane-parallel MLP fold (overlaps A-load latency) ----
    // lane d = lane&31; half 0 handles k={0,1}, half 1 handles k={2,3}
    const int  dd   = lane & 31;
    const int  half = lane >> 5;
    const float wd = w_start[dd];
    const float bd = b_start[dd];
    const float m0 = w_mlp[(2 * half + 0) * DD + dd];
    const float m1 = w_mlp[(2 * half + 1) * DD + dd];
    float p0 = wd * m0, q0 = bd * m0, r0 = m0;
    float p1 = wd * m1, q1 = bd * m1, r1 = m1;
#pragma unroll
    for (int mask = 1; mask <= 16; mask <<= 1) {
        p0 += __shfl_xor(p0, mask, 64);  q0 += __shfl_xor(q0, mask, 64);  r0 += __shfl_xor(r0, mask, 64);
        p1 += __shfl_xor(p1, mask, 64);  q1 += __shfl_xor(q1, mask, 64);  r1 += __shfl_xor(r1, mask, 64);
    }
    const float po0 = __shfl_xor(p0, 32, 64), qo0 = __shfl_xor(q0, 32, 64), ro0 = __shfl_xor(r0, 32, 64);
    const float po1 = __shfl_xor(p1, 32, 64), qo1 = __shfl_xor(q1, 32, 64), ro1 = __shfl_xor(r1, 32, 64);
    const bool lo = (half == 0);
    const float P0 = lo ? p0  : po0, P1 = lo ? p1  : po1, P2 = lo ? po0 : p0, P3 = lo ? po1 : p1;
    const float Q0 = lo ? q0  : qo0, Q1 = lo ? q1  : qo1, Q2 = lo ? qo0 : q0, Q3 = lo ? qo1 : q1;
    const float R1 = lo ? r1  : ro1, R2 = lo ? ro0 : r0,  R3 = lo ? ro1 : r1;

    const float Pp0 = P0 + BETA * (R1 + R2 + R3);
    const float Pp1 = P1 + BETA * (R2 + R3);
    const float Pp2 = P2 + BETA * R3;
    const float Pp3 = P3;
    const float c0  = Q0 + b_mlp[0];
    const float PpA[4] = {Pp0, Pp1, Pp2, Pp3};
    const float QA[4]  = {Q0, Q1, Q2, Q3};

    // ---- per-wave broadcast buffer ----
    __shared__ __align__(16) float2 yu[4][NN];

    const float xv = x[(size_t)(b * NN + lane) * SS + s];
    yu[w][lane] = make_float2(xv, 1.0f);
    WAITLDS();

    // acc init from y0 at this lane's 4 columns
    const float4 t01 = *reinterpret_cast<const float4*>(&yu[w][4 * q]);
    const float4 t23 = *reinterpret_cast<const float4*>(&yu[w][4 * q + 2]);
    float acc0 = fmaf(Pp0, t01.x, c0);
    float acc1 = fmaf(Pp0, t01.z, c0);
    float acc2 = fmaf(Pp0, t23.x, c0);
    float acc3 = fmaf(Pp0, t23.z, c0);

#pragma unroll
    for (int k = 1; k <= 3; ++k) {
        float ys0 = 0.f, ys1 = 0.f, ys2 = 0.f, ys3 = 0.f;
        float us0 = 0.f, us1 = 0.f, us2 = 0.f, us3 = 0.f;
#pragma unroll
        for (int i = 0; i < 16; ++i) {
            const float2 t = yu[w][4 * i + h];   // 4 distinct addrs, 4 distinct banks
            ys0 = fmaf(av[i].x, t.x, ys0);  us0 = fmaf(av[i].x, t.y, us0);
            ys1 = fmaf(av[i].y, t.x, ys1);  us1 = fmaf(av[i].y, t.y, us1);
            ys2 = fmaf(av[i].z, t.x, ys2);  us2 = fmaf(av[i].z, t.y, us2);
            ys3 = fmaf(av[i].w, t.x, ys3);  us3 = fmaf(av[i].w, t.y, us3);
        }
        // complete column sums across row-residue classes
        ys0 += __shfl_xor(ys0, 16, 64);  ys0 += __shfl_xor(ys0, 32, 64);
        ys1 += __shfl_xor(ys1, 16, 64);  ys1 += __shfl_xor(ys1, 32, 64);
        ys2 += __shfl_xor(ys2, 16, 64);  ys2 += __shfl_xor(ys2, 32, 64);
        ys3 += __shfl_xor(ys3, 16, 64);  ys3 += __shfl_xor(ys3, 32, 64);
        us0 += __shfl_xor(us0, 16, 64);  us0 += __shfl_xor(us0, 32, 64);
        us1 += __shfl_xor(us1, 16, 64);  us1 += __shfl_xor(us1, 32, 64);
        us2 += __shfl_xor(us2, 16, 64);  us2 += __shfl_xor(us2, 32, 64);
        us3 += __shfl_xor(us3, 16, 64);  us3 += __shfl_xor(us3, 32, 64);
        ys0 *= OMB; ys1 *= OMB; ys2 *= OMB; ys3 *= OMB;
        us0 *= OMB; us1 *= OMB; us2 *= OMB; us3 *= OMB;

        acc0 = fmaf(PpA[k], ys0, fmaf(QA[k], us0, acc0));
        acc1 = fmaf(PpA[k], ys1, fmaf(QA[k], us1, acc1));
        acc2 = fmaf(PpA[k], ys2, fmaf(QA[k], us2, acc2));
        acc3 = fmaf(PpA[k], ys3, fmaf(QA[k], us3, acc3));

        if (k < 3) {
            if (h == 0) {   // one copy per column group writes the new (y,u)
                *reinterpret_cast<float4*>(&yu[w][4 * q])     = make_float4(ys0, us0, ys1, us1);
                *reinterpret_cast<float4*>(&yu[w][4 * q + 2]) = make_float4(ys2, us2, ys3, us3);
            }
            WAITLDS();
        }
    }

    // ---- transpose through LDS for float4-coalesced stores along s ----
    __shared__ __align__(16) float res[NN][4];
    if (h == 0) {
        res[4 * q + 0][w] = acc0;
        res[4 * q + 1][w] = acc1;
        res[4 * q + 2][w] = acc2;
        res[4 * q + 3][w] = acc3;
    }
    __syncthreads();
    if (w == 0) {
        const float4 v = *reinterpret_cast<const float4*>(res[lane]);
        *reinterpret_cast<float4*>(&out[(size_t)(b * NN + lane) * SS + s4 * 4]) = v;
    }
}

extern "C" void kernel_launch(void* const* d_in, const int* in_sizes, int n_in,
                              void* d_out, int out_size, void* d_ws, size_t ws_size,
                              hipStream_t stream) {
    const float* x       = (const float*)d_in[0];
    const float* adj     = (const float*)d_in[1];
    const float* w_start = (const float*)d_in[2];
    const float* b_start = (const float*)d_in[3];
    const float* w_mlp   = (const float*)d_in[4];
    const float* b_mlp   = (const float*)d_in[5];
    float* out = (float*)d_out;

    const int grid = BB * (SS / 4);      // 32 * 84 = 2688 blocks, 4 waves each
    dgra_collapsed_kernel<<<grid, 256, 0, stream>>>(x, adj, w_start, b_start, w_mlp, b_mlp, out);
}

// Round 3
// 35.874 us; speedup vs baseline: 4.2750x; 4.2750x over previous
//
#include <hip/hip_runtime.h>

// DGraFormer graph-propagation block, algebraically collapsed to 6 matvecs
// of A=adj[b,s,:,:] (64x64) per (b,s):
//   out[n] = sum_k P'_k y_k[n] + sum_k Q_k u_k[n] + (Q_0 + b_mlp)
// with y_k = (0.95 A^T)^k x[b,:,s], u_k = (0.95 A^T)^k 1.
// Memory-bound: one streaming pass over adj (176 MB) => ~29 us floor.
//
// Round-3 notes:
//  - NO __launch_bounds__ min-waves arg: round 2's (256,4) made the allocator
//    target 64 VGPRs and spill the 64-reg A-tile to scratch (WRITE_SIZE 346 MB,
//    4x regression). Plain (256) kept A in registers in round 1.
//  - A layout: lane = 32*hi + c holds cols {2c,2c+1} of rows == hi (mod 2);
//    32x global_load_dwordx2, 512 B contiguous per instruction.
//  - matvec: 32x (broadcast ds_read_b64 + 4 fma), one shfl_xor(32) to combine
//    row-parity partials.
//  - MLP fold lane-parallel + shfl butterfly (was 384 redundant FMAs/thread).

#define BB 32
#define NN 64
#define SS 336
#define DD 32
#define BETA 0.05f
#define OMB 0.95f

#define WAITLDS() __asm__ volatile("s_waitcnt lgkmcnt(0)" ::: "memory")

__global__ __launch_bounds__(256) void dgra_collapsed_kernel(
    const float* __restrict__ x, const float* __restrict__ adj,
    const float* __restrict__ w_start, const float* __restrict__ b_start,
    const float* __restrict__ w_mlp, const float* __restrict__ b_mlp,
    float* __restrict__ out)
{
    const int tid  = threadIdx.x;
    const int lane = tid & 63;
    const int w    = tid >> 6;           // wave id = s within the s4 tile
    const int blk  = blockIdx.x;
    const int b    = blk / (SS / 4);
    const int s4   = blk % (SS / 4);
    const int s    = s4 * 4 + w;

    const int c  = lane & 31;            // column pair: cols 2c, 2c+1
    const int hi = lane >> 5;            // row parity

    // ---- stage A: 32 x dwordx2; av[i] = { A[2i+hi][2c], A[2i+hi][2c+1] } ----
    const float* Ab = adj + (size_t)(b * SS + s) * (NN * NN);
    float2 av[32];
#pragma unroll
    for (int i = 0; i < 32; ++i)
        av[i] = *reinterpret_cast<const float2*>(Ab + (2 * i + hi) * NN + 2 * c);

    const float xv = x[(size_t)(b * NN + lane) * SS + s];

    // ---- lane-parallel MLP fold (overlaps load latency) ----
    // lane d = lane&31; half 0 handles k={0,1}, half 1 handles k={2,3}
    const float wd = w_start[c];
    const float bd = b_start[c];
    const float m0 = w_mlp[(2 * hi + 0) * DD + c];
    const float m1 = w_mlp[(2 * hi + 1) * DD + c];
    float p0 = wd * m0, q0 = bd * m0, r0 = m0;
    float p1 = wd * m1, q1 = bd * m1, r1 = m1;
#pragma unroll
    for (int mask = 1; mask <= 16; mask <<= 1) {
        p0 += __shfl_xor(p0, mask, 64);  q0 += __shfl_xor(q0, mask, 64);  r0 += __shfl_xor(r0, mask, 64);
        p1 += __shfl_xor(p1, mask, 64);  q1 += __shfl_xor(q1, mask, 64);  r1 += __shfl_xor(r1, mask, 64);
    }
    const float po0 = __shfl_xor(p0, 32, 64), qo0 = __shfl_xor(q0, 32, 64), ro0 = __shfl_xor(r0, 32, 64);
    const float po1 = __shfl_xor(p1, 32, 64), qo1 = __shfl_xor(q1, 32, 64), ro1 = __shfl_xor(r1, 32, 64);
    const bool lo = (hi == 0);
    const float P0 = lo ? p0  : po0, P1 = lo ? p1  : po1, P2 = lo ? po0 : p0, P3 = lo ? po1 : p1;
    const float Q0 = lo ? q0  : qo0, Q1 = lo ? q1  : qo1, Q2 = lo ? qo0 : q0, Q3 = lo ? qo1 : q1;
    const float R1 = lo ? r1  : ro1, R2 = lo ? ro0 : r0,  R3 = lo ? ro1 : r1;

    const float Pp0 = P0 + BETA * (R1 + R2 + R3);
    const float c0  = Q0 + b_mlp[0];
    const float PpA[4] = {Pp0, P1 + BETA * (R2 + R3), P2 + BETA * R3, P3};
    const float QA[4]  = {Q0, Q1, Q2, Q3};

    // ---- per-wave (y,u) broadcast buffer ----
    __shared__ __align__(16) float2 yu[4][NN];
    yu[w][lane] = make_float2(xv, 1.0f);
    WAITLDS();

    // acc init from y0 at this lane's 2 columns
    const float4 t01 = *reinterpret_cast<const float4*>(&yu[w][2 * c]);  // {y2c,1,y2c+1,1}
    float acc0 = fmaf(Pp0, t01.x, c0);
    float acc1 = fmaf(Pp0, t01.z, c0);

#pragma unroll
    for (int k = 1; k <= 3; ++k) {
        float ys0 = 0.f, ys1 = 0.f, us0 = 0.f, us1 = 0.f;
#pragma unroll
        for (int i = 0; i < 32; ++i) {
            const float2 t = yu[w][2 * i + hi];  // 2 distinct addrs -> broadcast
            ys0 = fmaf(av[i].x, t.x, ys0);
            ys1 = fmaf(av[i].y, t.x, ys1);
            us0 = fmaf(av[i].x, t.y, us0);
            us1 = fmaf(av[i].y, t.y, us1);
        }
        // combine the two row-parity partials
        ys0 += __shfl_xor(ys0, 32, 64);
        ys1 += __shfl_xor(ys1, 32, 64);
        us0 += __shfl_xor(us0, 32, 64);
        us1 += __shfl_xor(us1, 32, 64);
        ys0 *= OMB; ys1 *= OMB; us0 *= OMB; us1 *= OMB;

        acc0 = fmaf(PpA[k], ys0, fmaf(QA[k], us0, acc0));
        acc1 = fmaf(PpA[k], ys1, fmaf(QA[k], us1, acc1));

        if (k < 3) {
            if (hi == 0)
                *reinterpret_cast<float4*>(&yu[w][2 * c]) = make_float4(ys0, us0, ys1, us1);
            WAITLDS();
        }
    }

    // ---- transpose through LDS for float4-coalesced stores along s ----
    __shared__ __align__(16) float res[NN][4];
    if (hi == 0) {
        res[2 * c + 0][w] = acc0;
        res[2 * c + 1][w] = acc1;
    }
    __syncthreads();
    if (w == 0) {
        const float4 v = *reinterpret_cast<const float4*>(res[lane]);
        *reinterpret_cast<float4*>(&out[(size_t)(b * NN + lane) * SS + s4 * 4]) = v;
    }
}

extern "C" void kernel_launch(void* const* d_in, const int* in_sizes, int n_in,
                              void* d_out, int out_size, void* d_ws, size_t ws_size,
                              hipStream_t stream) {
    const float* x       = (const float*)d_in[0];
    const float* adj     = (const float*)d_in[1];
    const float* w_start = (const float*)d_in[2];
    const float* b_start = (const float*)d_in[3];
    const float* w_mlp   = (const float*)d_in[4];
    const float* b_mlp   = (const float*)d_in[5];
    float* out = (float*)d_out;

    const int grid = BB * (SS / 4);      // 32 * 84 = 2688 blocks, 4 waves each
    dgra_collapsed_kernel<<<grid, 256, 0, stream>>>(x, adj, w_start, b_start, w_mlp, b_mlp, out);
}